// Round 10
// baseline (94.433 us; speedup 1.0000x reference)
//
#include <hip/hip_runtime.h>
#include <math.h>

#define ALPHA 0.7f
#define BETTA 0.3f
#define EPS   1e-8f

#define BLOCK 64                          // one wave per block
#define RPT   4                           // rows per thread
#define TILE_ROWS (BLOCK * RPT)           // 256 rows / block
#define TILE_F4   (TILE_ROWS * 3 / 4)     // 192 float4 per input per tile
#define TILE_DW   (TILE_ROWS * 3)         // 768 dwords per input per tile
#define LDS_DW    (TILE_DW + TILE_DW / 12)  // 832 (pad 1 per 12)

__device__ __forceinline__ void row_contrib(float x1, float y1, float z1,
                                            float x2, float y2, float z2,
                                            float& a0, float& a1, float& a2,
                                            float& ac) {
    float q1 = x1 * x1 + y1 * y1 + z1 * z1;
    float m = (q1 > EPS * EPS) ? 1.0f : 0.0f;
    float inv1 = (q1 > 0.0f) ? rsqrtf(q1) : 0.0f;
    float n1x = x1 * inv1, n1y = y1 * inv1, n1z = z1 * inv1;

    float q2 = x2 * x2 + y2 * y2 + z2 * z2;
    float inv2 = (q2 > 0.0f) ? rsqrtf(q2) : 0.0f;
    float u2x = x2 * inv2, u2y = y2 * inv2, u2z = z2 * inv2;

    float c = n1x * u2x + n1y * u2y + n1z * u2z;
    c = fminf(1.0f, fmaxf(-1.0f, c));
    float sin_a = sqrtf(fmaxf(0.0f, 1.0f - c * c));
    float cm1 = c - 1.0f;

    float d = n1x * x2 + n1y * y2 + n1z * z2;
    float wx = x2 - n1x * d, wy = y2 - n1y * d, wz = z2 - n1z * d;
    float wq = wx * wx + wy * wy + wz * wz;
    float invw = (wq > 0.0f) ? rsqrtf(wq) : 0.0f;
    float n2x = wx * invw, n2y = wy * invw, n2z = wz * invw;

    float s1 = n1x + n1y + n1z;
    float s2 = n2x + n2y + n2z;

    float tax = sin_a * (n2x * s1 - n1x * s2);
    float tay = sin_a * (n2y * s1 - n1y * s2);
    float taz = sin_a * (n2z * s1 - n1z * s2);

    float tbx = cm1 * (n1x * s1 + n2x * s2);
    float tby = cm1 * (n1y * s1 + n2y * s2);
    float tbz = cm1 * (n1z * s1 + n2z * s2);

    a0 += (ALPHA * tax * tax + BETTA * tbx * tbx) * m;
    a1 += (ALPHA * tay * tay + BETTA * tby * tby) * m;
    a2 += (ALPHA * taz * taz + BETTA * tbz * tbz) * m;
    ac += m;
}

// padded scatter: logical dword L -> physical L + L/12 (pad 1 per 12)
__device__ __forceinline__ void lds_store_f4(float* lds, int L0, float4 v) {
    int q = L0 / 12;                // compiler -> magic mul
    int p = L0 + q;                 // L0%12 in {0,4,8}: float4 never crosses pad
    lds[p + 0] = v.x;
    lds[p + 1] = v.y;
    lds[p + 2] = v.z;
    lds[p + 3] = v.w;
}

// Single-wave blocks: 8192 independent waves, ~24 resident/CU, staggered
// retirement -> deep natural pipelining (breaks the R9 convoy where all
// blocks loaded, then all computed, in lockstep). Coalesced float4 loads,
// padded-LDS transpose (reads 12 contiguous dwords at 13*t: 13 coprime 32
// -> 2-way = free), per-wave shuffle tree, one float4 partial per block.
__global__ __launch_bounds__(BLOCK) void trl_reduce(const float* __restrict__ v1,
                                                    const float* __restrict__ v2,
                                                    float4* __restrict__ ws,
                                                    int n_rows, int n_tiles) {
    __shared__ float ldsA[LDS_DW];  // 3.33 KB
    __shared__ float ldsB[LDS_DW];  // 3.33 KB

    int t = threadIdx.x;            // 0..63 (lane == thread)
    float a0 = 0.0f, a1 = 0.0f, a2 = 0.0f, ac = 0.0f;

    if (blockIdx.x < (unsigned)n_tiles) {
        const float4* g1 = (const float4*)v1;
        const float4* g2 = (const float4*)v2;
        long base = (long)blockIdx.x * TILE_F4;

        // coalesced: lane i reads base + 64*j + i (unit stride across wave)
        float4 la0 = g1[base + 0 * BLOCK + t];
        float4 la1 = g1[base + 1 * BLOCK + t];
        float4 la2 = g1[base + 2 * BLOCK + t];
        float4 lb0 = g2[base + 0 * BLOCK + t];
        float4 lb1 = g2[base + 1 * BLOCK + t];
        float4 lb2 = g2[base + 2 * BLOCK + t];

        int u = 4 * t;
        lds_store_f4(ldsA, 0 * 256 + u, la0);
        lds_store_f4(ldsA, 1 * 256 + u, la1);
        lds_store_f4(ldsA, 2 * 256 + u, la2);
        lds_store_f4(ldsB, 0 * 256 + u, lb0);
        lds_store_f4(ldsB, 1 * 256 + u, lb1);
        lds_store_f4(ldsB, 2 * 256 + u, lb2);
        __syncthreads();  // single wave: compiles to a cheap lgkm drain

        float fA[12], fB[12];
        int rb = 13 * t;
#pragma unroll
        for (int k = 0; k < 12; ++k) fA[k] = ldsA[rb + k];
#pragma unroll
        for (int k = 0; k < 12; ++k) fB[k] = ldsB[rb + k];

        row_contrib(fA[0], fA[1], fA[2],  fB[0], fB[1], fB[2],  a0, a1, a2, ac);
        row_contrib(fA[3], fA[4], fA[5],  fB[3], fB[4], fB[5],  a0, a1, a2, ac);
        row_contrib(fA[6], fA[7], fA[8],  fB[6], fB[7], fB[8],  a0, a1, a2, ac);
        row_contrib(fA[9], fA[10], fA[11], fB[9], fB[10], fB[11], a0, a1, a2, ac);
    }

    // tail rows beyond the last full tile (unused at N=2^21)
    if (blockIdx.x == 0) {
        for (long r = (long)n_tiles * TILE_ROWS + t; r < n_rows; r += BLOCK) {
            const float* q1 = v1 + r * 3;
            const float* q2 = v2 + r * 3;
            row_contrib(q1[0], q1[1], q1[2], q2[0], q2[1], q2[2], a0, a1, a2, ac);
        }
    }

    // wave-64 shuffle reduction; lane 0 stores the block partial
    for (int off = 32; off > 0; off >>= 1) {
        a0 += __shfl_down(a0, off, 64);
        a1 += __shfl_down(a1, off, 64);
        a2 += __shfl_down(a2, off, 64);
        ac += __shfl_down(ac, off, 64);
    }
    if (t == 0) {
        float4 o;
        o.x = a0; o.y = a1; o.z = a2; o.w = ac;
        ws[blockIdx.x] = o;
    }
}

// Stage 2: one 256-thread block over nblocks (8192) float4 partials.
__global__ __launch_bounds__(256) void trl_final(const float4* __restrict__ ws,
                                                 float* __restrict__ out,
                                                 int nblocks) {
    float s0 = 0.0f, s1 = 0.0f, s2 = 0.0f, sc = 0.0f;
    for (int i = threadIdx.x; i < nblocks; i += 256) {
        float4 p = ws[i];
        s0 += p.x; s1 += p.y; s2 += p.z; sc += p.w;
    }
    for (int off = 32; off > 0; off >>= 1) {
        s0 += __shfl_down(s0, off, 64);
        s1 += __shfl_down(s1, off, 64);
        s2 += __shfl_down(s2, off, 64);
        sc += __shfl_down(sc, off, 64);
    }
    __shared__ float smem[4][4];
    int lane = threadIdx.x & 63;
    int wave = threadIdx.x >> 6;
    if (lane == 0) {
        smem[wave][0] = s0;
        smem[wave][1] = s1;
        smem[wave][2] = s2;
        smem[wave][3] = sc;
    }
    __syncthreads();
    if (threadIdx.x < 3) {
        float num = smem[0][threadIdx.x] + smem[1][threadIdx.x] +
                    smem[2][threadIdx.x] + smem[3][threadIdx.x];
        float cnt = smem[0][3] + smem[1][3] + smem[2][3] + smem[3][3];
        cnt = fmaxf(cnt, 1.0f);
        float v = num / cnt;
        if (isnan(v)) v = 0.0f;
        else if (isinf(v)) v = (v > 0.0f) ? 0.1f : -0.1f;
        out[threadIdx.x] = v;
    }
}

extern "C" void kernel_launch(void* const* d_in, const int* in_sizes, int n_in,
                              void* d_out, int out_size, void* d_ws, size_t ws_size,
                              hipStream_t stream) {
    const float* v1 = (const float*)d_in[0];
    const float* v2 = (const float*)d_in[1];
    float* out = (float*)d_out;
    float4* ws = (float4*)d_ws;

    int n_rows = in_sizes[0] / 3;
    int n_tiles = n_rows / TILE_ROWS;   // 8192 full tiles for N=2^21
    int grid = (n_tiles > 0) ? n_tiles : 1;

    trl_reduce<<<grid, BLOCK, 0, stream>>>(v1, v2, ws, n_rows, n_tiles);
    trl_final<<<1, 256, 0, stream>>>(ws, out, grid);
}